// Round 9
// baseline (1207.243 us; speedup 1.0000x reference)
//
#include <hip/hip_runtime.h>
#include <math.h>
#include <stdint.h>

// Problem constants: B=16, S=256, E=256, H=256, V=50000, L=9
#define BB 16
#define SS 256
#define LL 9
#define ROWS 4096
#define HP 272         // bytes per batch row of H in LDS (fp8)
#define AP 40          // A-tile LDS pitch (ushorts): conflict-free b128

typedef __attribute__((ext_vector_type(8))) short short8;   // 8 bf16
typedef __attribute__((ext_vector_type(4))) float f32x4;    // MFMA acc
typedef __attribute__((ext_vector_type(8))) int i32x8;      // 32B MX fragment

#define HSCALE 256.0f
#define LOG2E  1.44269504f
// per-gate weight pack constants: i,f,o = -LOG2E*1024; g = +2*LOG2E*512
#define WCONST 1477.3199f
#define SCALE_ONE 0x7F7F7F7Fu
#define SCALE_IFO 0x6D6D6D6Du
#define SCALE_G   0x6E6E6E6Eu

__device__ __forceinline__ unsigned short f2bf(float f) {
  unsigned u = __float_as_uint(f);
  return (unsigned short)((u + 0x7FFF + ((u >> 16) & 1)) >> 16);  // RNE
}
__device__ __forceinline__ float bf2f(unsigned short s) {
  return __uint_as_float(((unsigned)s) << 16);
}

// ---------------------------------------------------------------------------
// Embedding gather -> bf16 x0 [4096][256]
__global__ __launch_bounds__(256) void embed_bf16(
    const int* __restrict__ ids, const float* __restrict__ emb,
    unsigned short* __restrict__ x0) {
  int row = blockIdx.x;
  int id = ids[row];
  x0[(size_t)row * 256 + threadIdx.x] = f2bf(emb[(size_t)id * 256 + threadIdx.x]);
}

// ---------------------------------------------------------------------------
// Pack w_hh (ALL layers) into fp8 e4m3 MX B-fragments (K=128), log-domain consts.
__global__ __launch_bounds__(64) void pack_whh_mx(
    const float* __restrict__ w, unsigned* __restrict__ wfrag) {
  int nb = blockIdx.x, ks2 = blockIdx.y, z = blockIdx.z;  // z = layer*2+dir
  int lane = threadIdx.x, qq = lane >> 4, col = lane & 15;
  int g = nb >> 4;
  float csc = (g == 2) ? WCONST : -WCONST;
  const float* wp = w + (size_t)z * 1024 * 256 + (size_t)(nb * 16 + col) * 256 +
                    ks2 * 128 + qq * 32;
  unsigned* op = wfrag + (((size_t)(z * 64 + nb) * 2 + ks2) * 64 + lane) * 8;
#pragma unroll
  for (int u = 0; u < 8; ++u) {
    float v0 = wp[u * 4 + 0] * csc, v1 = wp[u * 4 + 1] * csc;
    float v2 = wp[u * 4 + 2] * csc, v3 = wp[u * 4 + 3] * csc;
    unsigned pk = __builtin_amdgcn_cvt_pk_fp8_f32(v0, v1, 0, false);
    pk = __builtin_amdgcn_cvt_pk_fp8_f32(v2, v3, pk, true);
    op[u] = pk;
  }
}

// ---------------------------------------------------------------------------
// biasPF[l][dir][n'] = (b_ih[n]+b_hh[n]) * cg(n'),  n' = j*4+g, n = g*256+j
__global__ __launch_bounds__(256) void bias_perm(
    const float* __restrict__ b2, float* __restrict__ biasPF) {
  int i = blockIdx.x * 256 + threadIdx.x;  // 0..8191
  int l = i >> 11, r = i & 2047;
  int dir = r >> 10, np = r & 1023;
  int n = ((np & 3) << 8) + (np >> 2);
  float cg = ((np & 3) == 2) ? (2.0f * LOG2E) : (-LOG2E);
  biasPF[i] = (b2[l * 4096 + dir * 2048 + n] + b2[l * 4096 + dir * 2048 + 1024 + n]) * cg;
}

// ---------------------------------------------------------------------------
// Pre-convert W_ih (all layers) to bf16 in MFMA B-FRAGMENT layout, cg folded:
// out idx = (((dir*64+ntile)*KC + kc)*64 + lane)*8 + j
//   where np = ntile*16+(lane&15), k = kc*32+(lane>>4)*8+j
__global__ __launch_bounds__(256) void prep_wih(
    const float* __restrict__ w_l0, const float* __restrict__ w_rest,
    unsigned short* __restrict__ wp) {
  int l = blockIdx.z;
  int K = l ? 512 : 256;
  int kcb = l ? 4 : 3;              // log2(KC), KC = K/32
  long total = (long)2 * 1024 * K;
  long idx = (long)blockIdx.x * 256 + threadIdx.x;
  if (idx >= total) return;
  int j = (int)(idx & 7);
  long r = idx >> 3;
  int lane = (int)(r & 63); r >>= 6;
  int kc = (int)(r & ((1 << kcb) - 1));
  long r2 = r >> kcb;
  int ntile = (int)(r2 & 63);
  int dir = (int)(r2 >> 6);
  int quad = lane >> 4, col = lane & 15;
  int np = ntile * 16 + col;
  int k = kc * 32 + quad * 8 + j;
  int nph = ((np & 3) << 8) + (np >> 2);
  float cg = ((np & 3) == 2) ? (2.0f * LOG2E) : (-LOG2E);
  const float* src = l ? (w_rest + (size_t)(l - 1) * 2 * 1024 * 512) : w_l0;
  size_t off = l ? (524288 + (size_t)(l - 1) * 1048576) : 0;
  wp[off + idx] = f2bf(src[((size_t)dir * 1024 + nph) * K + k] * cg);
}

// ---------------------------------------------------------------------------
// Pipelined bf16 MFMA GEMM, B direct-from-global in fragment layout.
// Block 256 thr (4 waves), tile M128 x N128, wave-tile 64x64, BK=32.
// A double-buffered in padded LDS (one barrier/iter); B-frags prefetched to regs.
__global__ __launch_bounds__(256) void gemm_xg_bfrag(
    const unsigned short* __restrict__ A, int K,
    const unsigned short* __restrict__ Bfrag,   // layer slice, frag layout
    const float* __restrict__ biasPF,
    unsigned short* __restrict__ xgP) {
  int dir = blockIdx.z;
  int n0 = blockIdx.x * 128, m0 = blockIdx.y * 128;
  int tid = threadIdx.x;
  int wv = tid >> 6, lane = tid & 63, quad = lane >> 4, col = lane & 15;
  int wm = wv & 1, wn = wv >> 1;
  __shared__ unsigned short As[2][128 * AP];

  int KC = K >> 5;
  const unsigned short* Bf = Bfrag + (size_t)dir * 64 * KC * 512;
  const unsigned short* bfp[4];
#pragma unroll
  for (int nt = 0; nt < 4; ++nt)
    bfp[nt] = Bf + (((size_t)((n0 >> 4) + wn * 4 + nt) * KC) * 64 + lane) * 8;

  int srow = tid >> 1;
  int scol = (tid & 1) * 16;
  const unsigned short* ga = A + (size_t)(m0 + srow) * K + scol;
  int woff = srow * AP + scol;

  f32x4 acc[4][4];
#pragma unroll
  for (int mt = 0; mt < 4; ++mt)
#pragma unroll
    for (int nt = 0; nt < 4; ++nt) acc[mt][nt] = (f32x4){0.f, 0.f, 0.f, 0.f};

  // preload chunk 0
  short8 a0 = *(const short8*)ga;
  short8 a1 = *(const short8*)(ga + 8);
  short8 bcur[4];
#pragma unroll
  for (int nt = 0; nt < 4; ++nt) bcur[nt] = *(const short8*)bfp[nt];
  *(short8*)&As[0][woff] = a0;
  *(short8*)&As[0][woff + 8] = a1;
  __syncthreads();

  int cur = 0;
  for (int kc = 0; kc < KC; ++kc) {
    bool more = (kc + 1) < KC;
    short8 na0, na1, bnext[4];
    if (more) {
      na0 = *(const short8*)(ga + (kc + 1) * 32);
      na1 = *(const short8*)(ga + (kc + 1) * 32 + 8);
#pragma unroll
      for (int nt = 0; nt < 4; ++nt)
        bnext[nt] = *(const short8*)(bfp[nt] + (size_t)(kc + 1) * 512);
    }
    short8 af[4];
#pragma unroll
    for (int mt = 0; mt < 4; ++mt)
      af[mt] = *(const short8*)&As[cur][(wm * 64 + mt * 16 + col) * AP + quad * 8];
#pragma unroll
    for (int mt = 0; mt < 4; ++mt)
#pragma unroll
      for (int nt = 0; nt < 4; ++nt)
        acc[mt][nt] = __builtin_amdgcn_mfma_f32_16x16x32_bf16(af[mt], bcur[nt], acc[mt][nt], 0, 0, 0);
    if (more) {
      *(short8*)&As[cur ^ 1][woff] = na0;
      *(short8*)&As[cur ^ 1][woff + 8] = na1;
#pragma unroll
      for (int nt = 0; nt < 4; ++nt) bcur[nt] = bnext[nt];
    }
    __syncthreads();
    cur ^= 1;
  }

#pragma unroll
  for (int nt = 0; nt < 4; ++nt) {
    int np = n0 + wn * 64 + nt * 16 + col;
    float bia = biasPF[dir * 1024 + np];
#pragma unroll
    for (int mt = 0; mt < 4; ++mt) {
#pragma unroll
      for (int r = 0; r < 4; ++r) {
        int row = m0 + wm * 64 + mt * 16 + quad * 4 + r;
        xgP[((size_t)dir * ROWS + row) * 1024 + np] = f2bf(acc[mt][nt][r] + bia);
      }
    }
  }
}

// ---------------------------------------------------------------------------
// MX-fp8 (K=128) MFMA LSTM recurrence (round-7 structure; xq folded into C-init).
__global__ __launch_bounds__(512, 2) void lstm_mx(
    const unsigned short* __restrict__ xgP,   // [2][4096][1024] bf16 n'=j*4+g
    const unsigned* __restrict__ wfrag,       // layer slice: [2][64][2][64][8] dw
    unsigned short* __restrict__ xout) {      // [4096][512] bf16
  int dir = blockIdx.x & 1;
  int bg = blockIdx.x >> 1;            // 0..7 -> batches bg*2, bg*2+1
  int tid = threadIdx.x;
  int wv = tid >> 6, lane = tid & 63;
  int quad = lane >> 4, col = lane & 15;

  __shared__ __align__(16) unsigned char Hfrag[2][2 * HP];

  {
    int* hz = (int*)&Hfrag[0][0];
    for (int i = tid; i < HP; i += 512) hz[i] = 0;
  }

  i32x8 wf[2][4][2];
#pragma unroll
  for (int hbi = 0; hbi < 2; ++hbi)
#pragma unroll
    for (int g = 0; g < 4; ++g) {
      int nb = g * 16 + 2 * wv + hbi;
#pragma unroll
      for (int ks2 = 0; ks2 < 2; ++ks2)
        wf[hbi][g][ks2] = *(const i32x8*)(wfrag +
            (((size_t)(dir * 64 + nb) * 2 + ks2) * 64 + lane) * 8);
    }

  int aoff = ((lane & 15) >> 3) * HP + (lane >> 4) * 32;

  int hbsel = quad & 1;
  int bq = quad >> 1;
  int j = 32 * wv + 16 * hbsel + col;
  int b = bg * 2 + bq;
  int pos0 = dir ? (SS - 1) : 0;
  int dstep = dir ? -1 : 1;
  const unsigned short* xq_ptr =
      xgP + ((size_t)dir * ROWS + (size_t)b * SS + pos0) * 1024 + j * 4;
  unsigned short* xo_ptr = xout + ((size_t)b * SS + pos0) * 512 + dir * 256 + j;
  int xq_d = dstep * 1024;
  int xo_d = dstep * 512;
  int hw = bq * HP + j;

  float Cp = 0.f;                 // C' = 2*LOG2E * c
  unsigned short ph = 0;
  unsigned short* xo_prev = xo_ptr;
  int cur = 0;
  __syncthreads();

  for (int t = 0; t < SS; ++t) {
    if (t) *xo_prev = ph;
    ushort4 xq = *(const ushort4*)xq_ptr;
    xq_ptr += xq_d;
    float xg4[4] = {bf2f(xq.x), bf2f(xq.y), bf2f(xq.z), bf2f(xq.w)};

    i32x8 af0 = *(const i32x8*)&Hfrag[cur][aoff];
    i32x8 af1 = *(const i32x8*)&Hfrag[cur][aoff + 128];
    f32x4 acc[2][4];
#pragma unroll
    for (int hbi = 0; hbi < 2; ++hbi) {
#pragma unroll
      for (int g = 0; g < 4; ++g) {
        // xg folded into C[0] (the only consumed element of this lane's tile)
        f32x4 a = (f32x4){xg4[g], 0.f, 0.f, 0.f};
        a = __builtin_amdgcn_mfma_scale_f32_16x16x128_f8f6f4(
                af0, wf[hbi][g][0], a, 0, 0, 0, SCALE_ONE, 0,
                (g == 2) ? SCALE_G : SCALE_IFO);
        a = __builtin_amdgcn_mfma_scale_f32_16x16x128_f8f6f4(
                af1, wf[hbi][g][1], a, 0, 0, 0, SCALE_ONE, 0,
                (g == 2) ? SCALE_G : SCALE_IFO);
        acc[hbi][g] = a;
      }
    }

    int nxt = cur ^ 1;
    float gi = hbsel ? acc[1][0][0] : acc[0][0][0];
    float gf = hbsel ? acc[1][1][0] : acc[0][1][0];
    float gt = hbsel ? acc[1][2][0] : acc[0][2][0];
    float go = hbsel ? acc[1][3][0] : acc[0][3][0];
    float si = __builtin_amdgcn_rcpf(1.0f + __builtin_amdgcn_exp2f(gi));
    float sf = __builtin_amdgcn_rcpf(1.0f + __builtin_amdgcn_exp2f(gf));
    float so = __builtin_amdgcn_rcpf(1.0f + __builtin_amdgcn_exp2f(go));
    float rg = __builtin_amdgcn_rcpf(1.0f + __builtin_amdgcn_exp2f(gt));
    float tg2 = fmaf(-4.0f * LOG2E, rg, 2.0f * LOG2E);
    Cp = fmaf(sf, Cp, si * tg2);
    float rc = __builtin_amdgcn_rcpf(1.0f + __builtin_amdgcn_exp2f(Cp));
    float h = so * fmaf(-2.0f, rc, 1.0f);
    unsigned pk = __builtin_amdgcn_cvt_pk_fp8_f32(h * HSCALE, h * HSCALE, 0, false);
    Hfrag[nxt][hw] = (unsigned char)(pk & 0xFF);
    ph = f2bf(h);
    xo_prev = xo_ptr;
    xo_ptr += xo_d;
    __syncthreads();
    cur = nxt;
  }
  *xo_prev = ph;
}

// ---------------------------------------------------------------------------
// LayerNorm + 9-way linear. One wave per row. X is bf16 [4096][512].
__global__ __launch_bounds__(64) void ln_logits(
    const unsigned short* __restrict__ X, const float* __restrict__ g,
    const float* __restrict__ bt, const float* __restrict__ W,
    const float* __restrict__ lb, float* __restrict__ out) {
  int row = blockIdx.x;
  int lane = threadIdx.x;
  const unsigned short* x = X + (size_t)row * 512;
  float v[8];
  float s = 0.f, s2 = 0.f;
#pragma unroll
  for (int i = 0; i < 8; ++i) {
    v[i] = bf2f(x[lane + 64 * i]);
    s += v[i];
    s2 += v[i] * v[i];
  }
#pragma unroll
  for (int off = 32; off; off >>= 1) {
    s += __shfl_down(s, off, 64);
    s2 += __shfl_down(s2, off, 64);
  }
  s = __shfl(s, 0, 64);
  s2 = __shfl(s2, 0, 64);
  float mu = s * (1.f / 512.f);
  float var = s2 * (1.f / 512.f) - mu * mu;
  float rstd = rsqrtf(var + 1e-5f);
  float y[8];
#pragma unroll
  for (int i = 0; i < 8; ++i) {
    int e = lane + 64 * i;
    y[i] = (v[i] - mu) * rstd * g[e] + bt[e];
  }
  for (int l = 0; l < LL; ++l) {
    float p = 0.f;
#pragma unroll
    for (int i = 0; i < 8; ++i) p += y[i] * W[(size_t)l * 512 + lane + 64 * i];
#pragma unroll
    for (int off = 32; off; off >>= 1) p += __shfl_down(p, off, 64);
    if (lane == 0) out[(size_t)row * LL + l] = p + lb[l];
  }
}

// ---------------------------------------------------------------------------
// CRF numerator + denominator + loss. One block of 256 threads.
__global__ __launch_bounds__(256) void crf_kernel(
    const float* __restrict__ logits, const int* __restrict__ labels,
    const int* __restrict__ mask, const float* __restrict__ cs,
    const float* __restrict__ ce, const float* __restrict__ ct,
    float* __restrict__ loss_out) {
  __shared__ float trans[9][12];
  __shared__ float alpha[2][BB][12];
  __shared__ float numsh[BB];
  __shared__ float res[BB];
  int tid = threadIdx.x;
  int b = tid >> 4;
  int i = tid & 15;
  if (tid < 81) trans[tid / 9][tid % 9] = ct[tid];
  __syncthreads();
  const float* lg = logits + (size_t)b * SS * LL;
  const int* lbp = labels + (size_t)b * SS;
  const int* mk = mask + (size_t)b * SS;

  float np = 0.f;
  int msum = 0;
  for (int t = i; t < SS; t += 16) {
    msum += mk[t];
    if (t == 0) {
      int l0 = lbp[0];
      np += cs[l0] + lg[l0];
    } else {
      float m = (float)mk[t];
      np += (trans[lbp[t - 1]][lbp[t]] + lg[(size_t)t * LL + lbp[t]]) * m;
    }
  }
#pragma unroll
  for (int off = 8; off; off >>= 1) {
    np += __shfl_down(np, off, 16);
    msum += __shfl_down(msum, off, 16);
  }
  if (i == 0) {
    int last = msum - 1;
    numsh[b] = np + ce[lbp[last]];
  }

  if (i < LL) alpha[0][b][i] = cs[i] + lg[i];
  int cur = 0;
  for (int t = 1; t < SS; ++t) {
    if (i < LL) {
      float e = lg[(size_t)t * LL + i];
      float av[9];
      float mmax = -1e30f;
#pragma unroll
      for (int p = 0; p < LL; ++p) {
        float vv = alpha[cur][b][p] + trans[p][i];
        av[p] = vv;
        mmax = fmaxf(mmax, vv);
      }
      float ssum = 0.f;
#pragma unroll
      for (int p = 0; p < LL; ++p) ssum += __expf(av[p] - mmax);
      float anew = e + mmax + logf(ssum);
      float aold = alpha[cur][b][i];
      alpha[cur ^ 1][b][i] = (mk[t] > 0) ? anew : aold;
    }
    cur ^= 1;
  }
  if (i == 0) {
    float arr[9];
    float m2 = -1e30f;
#pragma unroll
    for (int cc = 0; cc < LL; ++cc) {
      arr[cc] = alpha[cur][b][cc] + ce[cc];
      m2 = fmaxf(m2, arr[cc]);
    }
    float ssd = 0.f;
#pragma unroll
    for (int cc = 0; cc < LL; ++cc) ssd += __expf(arr[cc] - m2);
    float denom = m2 + logf(ssd);
    res[b] = numsh[b] - denom;
  }
  __syncthreads();
  if (tid == 0) {
    float Lsum = 0.f;
    for (int b2 = 0; b2 < BB; ++b2) Lsum += res[b2];
    loss_out[0] = -Lsum;
  }
}

// ---------------------------------------------------------------------------
extern "C" void kernel_launch(void* const* d_in, const int* in_sizes, int n_in,
                              void* d_out, int out_size, void* d_ws, size_t ws_size,
                              hipStream_t stream) {
  const int* input_ids = (const int*)d_in[0];
  const int* attn_mask = (const int*)d_in[1];
  const int* labels = (const int*)d_in[2];
  const float* embedding = (const float*)d_in[3];
  const float* w_ih_l0 = (const float*)d_in[4];
  const float* w_ih_rest = (const float*)d_in[5];
  const float* w_hh = (const float*)d_in[6];
  const float* bvec = (const float*)d_in[7];
  const float* ln_g = (const float*)d_in[8];
  const float* ln_b = (const float*)d_in[9];
  const float* lin_w = (const float*)d_in[10];
  const float* lin_b = (const float*)d_in[11];
  const float* crf_start = (const float*)d_in[12];
  const float* crf_end = (const float*)d_in[13];
  const float* crf_trans = (const float*)d_in[14];
  float* out = (float*)d_out;
  char* base = (char*)d_ws;

  unsigned short* x0    = (unsigned short*)(base);                        // 2 MB
  unsigned short* xoutA = (unsigned short*)(base + (2u << 20));           // 4 MB
  unsigned short* xoutB = (unsigned short*)(base + (6u << 20));           // 4 MB
  unsigned short* xgP   = (unsigned short*)(base + (10u << 20));          // 16 MB
  unsigned*       wfrag = (unsigned*)(base + (26u << 20));                // 2 MB
  float*          biasPF= (float*)(base + (28u << 20));                   // 32 KB
  unsigned short* wihP  = (unsigned short*)(base + (29u << 20));          // 7 MB

  embed_bf16<<<ROWS, 256, 0, stream>>>(input_ids, embedding, x0);
  pack_whh_mx<<<dim3(64, 2, 8), 64, 0, stream>>>(w_hh, wfrag);
  bias_perm<<<32, 256, 0, stream>>>(bvec, biasPF);
  prep_wih<<<dim3(4096, 1, 4), 256, 0, stream>>>(w_ih_l0, w_ih_rest, wihP);

  // wihP per-layer offsets (ushorts): l0=0, l1=524288, l2=1572864, l3=2621440
  const size_t WOFF[4] = {0, 524288, 1572864, 2621440};

  const unsigned short* cur = x0;
  unsigned short* nxt = xoutA;
  for (int l = 0; l < 4; ++l) {
    int K = l ? 512 : 256;
    gemm_xg_bfrag<<<dim3(8, 32, 2), 256, 0, stream>>>(
        cur, K, wihP + WOFF[l], biasPF + (size_t)l * 2048, xgP);
    lstm_mx<<<16, 512, 0, stream>>>(xgP, wfrag + (size_t)l * 131072, nxt);
    cur = nxt;
    nxt = (nxt == xoutA) ? xoutB : xoutA;
  }

  ln_logits<<<ROWS, 64, 0, stream>>>(cur, ln_g, ln_b, lin_w, lin_b, out);
  crf_kernel<<<1, 256, 0, stream>>>(out, labels, attn_mask, crf_start, crf_end,
                                    crf_trans, out + (size_t)ROWS * LL);
}